// Round 1
// baseline (279.825 us; speedup 1.0000x reference)
//
#include <hip/hip_runtime.h>

static constexpr int NPTS  = 262144;
static constexpr int BATCH = 64;
static constexpr int BLKS1 = 16;   // blocks per batch, pass 1 (argmax y)
static constexpr int BLKS2 = 32;   // blocks per batch, pass 2 (dist argmax)

struct ValIdx { float v; int i; };

__device__ __forceinline__ void combine(float& bv, int& bi, float v, int i) {
    // first-occurrence argmax semantics: larger value wins; on tie, smaller index
    if (v > bv || (v == bv && i < bi)) { bv = v; bi = i; }
}

__device__ __forceinline__ void block_reduce_256(float& bv, int& bi) {
    // full 64-lane wave reduce (all lanes hold valid candidates)
    for (int off = 32; off > 0; off >>= 1) {
        float ov = __shfl_down(bv, off);
        int   oi = __shfl_down(bi, off);
        combine(bv, bi, ov, oi);
    }
    __shared__ float sv[4];
    __shared__ int   si[4];
    int wid  = threadIdx.x >> 6;
    int lane = threadIdx.x & 63;
    if (lane == 0) { sv[wid] = bv; si[wid] = bi; }
    __syncthreads();
    if (threadIdx.x == 0) {
        for (int w = 1; w < 4; ++w) combine(bv, bi, sv[w], si[w]);
    }
}

// Pass 1: per-batch argmax over Y plane (contiguous N floats at b*3N + N)
__global__ __launch_bounds__(256) void k_argmax_y(const float* __restrict__ xyz,
                                                  ValIdx* __restrict__ part) {
    int b   = blockIdx.x / BLKS1;
    int blk = blockIdx.x % BLKS1;
    const int chunk = NPTS / BLKS1;                       // 16384
    const float4* Y4 = (const float4*)(xyz + (size_t)b * 3 * NPTS + NPTS
                                       + (size_t)blk * chunk);
    int base = blk * chunk;
    float bv = -__builtin_inff();
    int   bi = 0x7fffffff;
    for (int j = threadIdx.x; j < chunk / 4; j += 256) {
        float4 y = Y4[j];
        int i0 = base + j * 4;
        combine(bv, bi, y.x, i0);
        combine(bv, bi, y.y, i0 + 1);
        combine(bv, bi, y.z, i0 + 2);
        combine(bv, bi, y.w, i0 + 3);
    }
    block_reduce_256(bv, bi);
    if (threadIdx.x == 0) part[blockIdx.x] = ValIdx{bv, bi};
}

// Finalize f0: reduce BLKS1 partials per batch, write out[2b], gather centroid
__global__ __launch_bounds__(64) void k_final_f0(const float* __restrict__ xyz,
                                                 const ValIdx* __restrict__ part,
                                                 int* __restrict__ out,
                                                 float* __restrict__ cent) {
    int b = blockIdx.x;
    int t = threadIdx.x;
    float bv = -__builtin_inff();
    int   bi = 0x7fffffff;
    if (t < BLKS1) { ValIdx p = part[b * BLKS1 + t]; bv = p.v; bi = p.i; }
    for (int off = 32; off > 0; off >>= 1) {
        float ov = __shfl_down(bv, off);
        int   oi = __shfl_down(bi, off);
        combine(bv, bi, ov, oi);
    }
    if (t == 0) {
        out[b * 2 + 0] = bi;
        const float* base = xyz + (size_t)b * 3 * NPTS;
        cent[b * 3 + 0] = base[bi];
        cent[b * 3 + 1] = base[NPTS + bi];
        cent[b * 3 + 2] = base[2 * NPTS + bi];
    }
}

// Pass 2: per-batch argmax of squared distance to centroid
__global__ __launch_bounds__(256) void k_dist_argmax(const float* __restrict__ xyz,
                                                     const float* __restrict__ cent,
                                                     ValIdx* __restrict__ part) {
#pragma clang fp contract(off)
    int b   = blockIdx.x / BLKS2;
    int blk = blockIdx.x % BLKS2;
    const int chunk = NPTS / BLKS2;                       // 8192
    const float* base = xyz + (size_t)b * 3 * NPTS + (size_t)blk * chunk;
    const float4* X4 = (const float4*)base;
    const float4* Y4 = (const float4*)(base + NPTS);
    const float4* Z4 = (const float4*)(base + 2 * NPTS);
    float cx = cent[b * 3 + 0];
    float cy = cent[b * 3 + 1];
    float cz = cent[b * 3 + 2];
    int ib = blk * chunk;
    float bv = -__builtin_inff();
    int   bi = 0x7fffffff;
    for (int j = threadIdx.x; j < chunk / 4; j += 256) {
        float4 x = X4[j], y = Y4[j], z = Z4[j];
        int i0 = ib + j * 4;
        {
            float dx = x.x - cx, dy = y.x - cy, dz = z.x - cz;
            float d = (dx * dx + dy * dy) + dz * dz;
            combine(bv, bi, d, i0);
        }
        {
            float dx = x.y - cx, dy = y.y - cy, dz = z.y - cz;
            float d = (dx * dx + dy * dy) + dz * dz;
            combine(bv, bi, d, i0 + 1);
        }
        {
            float dx = x.z - cx, dy = y.z - cy, dz = z.z - cz;
            float d = (dx * dx + dy * dy) + dz * dz;
            combine(bv, bi, d, i0 + 2);
        }
        {
            float dx = x.w - cx, dy = y.w - cy, dz = z.w - cz;
            float d = (dx * dx + dy * dy) + dz * dz;
            combine(bv, bi, d, i0 + 3);
        }
    }
    block_reduce_256(bv, bi);
    if (threadIdx.x == 0) part[blockIdx.x] = ValIdx{bv, bi};
}

// Finalize f1: reduce BLKS2 partials per batch, write out[2b+1]
__global__ __launch_bounds__(64) void k_final_f1(const ValIdx* __restrict__ part,
                                                 int* __restrict__ out) {
    int b = blockIdx.x;
    int t = threadIdx.x;
    float bv = -__builtin_inff();
    int   bi = 0x7fffffff;
    if (t < BLKS2) { ValIdx p = part[b * BLKS2 + t]; bv = p.v; bi = p.i; }
    for (int off = 32; off > 0; off >>= 1) {
        float ov = __shfl_down(bv, off);
        int   oi = __shfl_down(bi, off);
        combine(bv, bi, ov, oi);
    }
    if (t == 0) out[b * 2 + 1] = bi;
}

extern "C" void kernel_launch(void* const* d_in, const int* in_sizes, int n_in,
                              void* d_out, int out_size, void* d_ws, size_t ws_size,
                              hipStream_t stream) {
    const float* xyz = (const float*)d_in[0];
    int* out = (int*)d_out;
    char* ws = (char*)d_ws;
    // ws layout: part1 [1024 ValIdx = 8192 B] | cent [64*3 f32, pad to 1024 B] | part2 [2048 ValIdx]
    ValIdx* part1 = (ValIdx*)ws;
    float*  cent  = (float*)(ws + 8192);
    ValIdx* part2 = (ValIdx*)(ws + 9216);

    k_argmax_y  <<<BATCH * BLKS1, 256, 0, stream>>>(xyz, part1);
    k_final_f0  <<<BATCH,         64,  0, stream>>>(xyz, part1, out, cent);
    k_dist_argmax<<<BATCH * BLKS2, 256, 0, stream>>>(xyz, cent, part2);
    k_final_f1  <<<BATCH,         64,  0, stream>>>(part2, out);
}

// Round 2
// 274.939 us; speedup vs baseline: 1.0178x; 1.0178x over previous
//
#include <hip/hip_runtime.h>
#include <stdint.h>

static constexpr int NPTS  = 262144;
static constexpr int BATCH = 64;
static constexpr int BLKS1 = 32;   // blocks per batch, pass 1 (argmax y)
static constexpr int BLKS2 = 32;   // blocks per batch, pass 2 (dist argmax)

// ---- branchless packed argmax ----------------------------------------------
// key = (order_preserving_bits(value) << 32) | ~index
// max(key) == (max value, and among ties the SMALLEST index)  -> matches
// jnp.argmax first-occurrence semantics. All keys > 0 since ~index > 0.

__device__ __forceinline__ uint32_t map_f32(float f) {
    uint32_t u = __float_as_uint(f);
    // monotone map: negative floats -> [0, 0x80000000), positive -> [0x80000000, ...]
    return (u & 0x80000000u) ? ~u : (u | 0x80000000u);
}

__device__ __forceinline__ uint64_t pack_key(uint32_t vbits, int i) {
    return ((uint64_t)vbits << 32) | (uint32_t)(~i);
}

__device__ __forceinline__ uint64_t umax64(uint64_t a, uint64_t b) {
    return a > b ? a : b;
}

// full 256-thread block max of u64 keys; valid result in thread 0
__device__ __forceinline__ uint64_t block_max_256(uint64_t k) {
    for (int off = 32; off > 0; off >>= 1)
        k = umax64(k, (uint64_t)__shfl_down((unsigned long long)k, off));
    __shared__ uint64_t s[4];
    int wid  = threadIdx.x >> 6;
    int lane = threadIdx.x & 63;
    if (lane == 0) s[wid] = k;
    __syncthreads();
    if (threadIdx.x == 0)
        for (int w = 1; w < 4; ++w) k = umax64(k, s[w]);
    return k;
}

// ---- pass 1: per-batch argmax over Y plane ---------------------------------
__global__ __launch_bounds__(256) void k_argmax_y(const float* __restrict__ xyz,
                                                  uint64_t* __restrict__ part) {
    int b   = blockIdx.x / BLKS1;
    int blk = blockIdx.x % BLKS1;
    const int chunk = NPTS / BLKS1;                       // 8192
    const float4* Y4 = (const float4*)(xyz + (size_t)b * 3 * NPTS + NPTS
                                       + (size_t)blk * chunk);
    int base = blk * chunk;
    uint64_t bk = 0;
#pragma unroll 4
    for (int j = threadIdx.x; j < chunk / 4; j += 256) {
        float4 y = Y4[j];
        int i0 = base + j * 4;
        bk = umax64(bk, pack_key(map_f32(y.x), i0));
        bk = umax64(bk, pack_key(map_f32(y.y), i0 + 1));
        bk = umax64(bk, pack_key(map_f32(y.z), i0 + 2));
        bk = umax64(bk, pack_key(map_f32(y.w), i0 + 3));
    }
    bk = block_max_256(bk);
    if (threadIdx.x == 0) part[blockIdx.x] = bk;
}

// ---- finalize f0: reduce partials, write out[2b], gather centroid ----------
__global__ __launch_bounds__(64) void k_final_f0(const float* __restrict__ xyz,
                                                 const uint64_t* __restrict__ part,
                                                 int* __restrict__ out,
                                                 float* __restrict__ cent) {
    int b = blockIdx.x;
    int t = threadIdx.x;
    uint64_t k = (t < BLKS1) ? part[b * BLKS1 + t] : 0;
    for (int off = 32; off > 0; off >>= 1)
        k = umax64(k, (uint64_t)__shfl_down((unsigned long long)k, off));
    if (t == 0) {
        int bi = (int)(~(uint32_t)k);
        out[b * 2 + 0] = bi;
        const float* base = xyz + (size_t)b * 3 * NPTS;
        cent[b * 3 + 0] = base[bi];
        cent[b * 3 + 1] = base[NPTS + bi];
        cent[b * 3 + 2] = base[2 * NPTS + bi];
    }
}

// ---- pass 2: per-batch argmax of squared distance to centroid --------------
__global__ __launch_bounds__(256) void k_dist_argmax(const float* __restrict__ xyz,
                                                     const float* __restrict__ cent,
                                                     uint64_t* __restrict__ part) {
#pragma clang fp contract(off)
    int b   = blockIdx.x / BLKS2;
    int blk = blockIdx.x % BLKS2;
    const int chunk = NPTS / BLKS2;                       // 8192
    const float* base = xyz + (size_t)b * 3 * NPTS + (size_t)blk * chunk;
    const float4* X4 = (const float4*)base;
    const float4* Y4 = (const float4*)(base + NPTS);
    const float4* Z4 = (const float4*)(base + 2 * NPTS);
    float cx = cent[b * 3 + 0];
    float cy = cent[b * 3 + 1];
    float cz = cent[b * 3 + 2];
    int ib = blk * chunk;
    uint64_t bk = 0;
#pragma unroll 4
    for (int j = threadIdx.x; j < chunk / 4; j += 256) {
        float4 x = X4[j], y = Y4[j], z = Z4[j];
        int i0 = ib + j * 4;
        // distances are >= 0, so raw float bits are already order-preserving
        {
            float dx = x.x - cx, dy = y.x - cy, dz = z.x - cz;
            float d = (dx * dx + dy * dy) + dz * dz;
            bk = umax64(bk, pack_key(__float_as_uint(d), i0));
        }
        {
            float dx = x.y - cx, dy = y.y - cy, dz = z.y - cz;
            float d = (dx * dx + dy * dy) + dz * dz;
            bk = umax64(bk, pack_key(__float_as_uint(d), i0 + 1));
        }
        {
            float dx = x.z - cx, dy = y.z - cy, dz = z.z - cz;
            float d = (dx * dx + dy * dy) + dz * dz;
            bk = umax64(bk, pack_key(__float_as_uint(d), i0 + 2));
        }
        {
            float dx = x.w - cx, dy = y.w - cy, dz = z.w - cz;
            float d = (dx * dx + dy * dy) + dz * dz;
            bk = umax64(bk, pack_key(__float_as_uint(d), i0 + 3));
        }
    }
    bk = block_max_256(bk);
    if (threadIdx.x == 0) part[blockIdx.x] = bk;
}

// ---- finalize f1: reduce partials, write out[2b+1] -------------------------
__global__ __launch_bounds__(64) void k_final_f1(const uint64_t* __restrict__ part,
                                                 int* __restrict__ out) {
    int b = blockIdx.x;
    int t = threadIdx.x;
    uint64_t k = (t < BLKS2) ? part[b * BLKS2 + t] : 0;
    for (int off = 32; off > 0; off >>= 1)
        k = umax64(k, (uint64_t)__shfl_down((unsigned long long)k, off));
    if (t == 0) out[b * 2 + 1] = (int)(~(uint32_t)k);
}

extern "C" void kernel_launch(void* const* d_in, const int* in_sizes, int n_in,
                              void* d_out, int out_size, void* d_ws, size_t ws_size,
                              hipStream_t stream) {
    const float* xyz = (const float*)d_in[0];
    int* out = (int*)d_out;
    char* ws = (char*)d_ws;
    // ws layout: part1 [2048 u64 = 16 KB] | cent [64*3 f32, pad to 1 KB] | part2 [2048 u64]
    uint64_t* part1 = (uint64_t*)ws;
    float*    cent  = (float*)(ws + 16384);
    uint64_t* part2 = (uint64_t*)(ws + 17408);

    k_argmax_y   <<<BATCH * BLKS1, 256, 0, stream>>>(xyz, part1);
    k_final_f0   <<<BATCH,         64,  0, stream>>>(xyz, part1, out, cent);
    k_dist_argmax<<<BATCH * BLKS2, 256, 0, stream>>>(xyz, cent, part2);
    k_final_f1   <<<BATCH,         64,  0, stream>>>(part2, out);
}